// Round 1
// baseline (415.440 us; speedup 1.0000x reference)
//
#include <hip/hip_runtime.h>
#include <stdint.h>

#define B_ 4
#define S_ 2048
#define D_ 1024
#define H_ 16
#define DK_ 64
#define M_ (B_*S_)   // 8192

typedef __attribute__((ext_vector_type(8))) short short8;
typedef __attribute__((ext_vector_type(4))) float f32x4;

static __device__ __forceinline__ float bf2f(unsigned short s) {
  union { unsigned u; float f; } v; v.u = ((unsigned)s) << 16; return v.f;
}
static __device__ __forceinline__ unsigned short f2bf(float f) {
  union { float f; unsigned u; } v; v.f = f;
  unsigned r = v.u + 0x7fffu + ((v.u >> 16) & 1u);
  return (unsigned short)(r >> 16);
}

#define GLDS16(g, l) __builtin_amdgcn_global_load_lds( \
    (const __attribute__((address_space(1))) unsigned int*)(g), \
    (__attribute__((address_space(3))) unsigned int*)(l), 16, 0, 0)

// ---------------- fp32 -> bf16 convert ----------------
__global__ void cvt_kernel(const float* __restrict__ in, unsigned short* __restrict__ out, int n4) {
  int i = blockIdx.x * 256 + threadIdx.x;
  if (i >= n4) return;
  float4 v = ((const float4*)in)[i];
  ushort4 o;
  o.x = f2bf(v.x); o.y = f2bf(v.y); o.z = f2bf(v.z); o.w = f2bf(v.w);
  ((ushort4*)out)[i] = o;
}

// ---------------- GEMM: C[M,N] = A[M,K] * W[N,K]^T, M=8192,N=K=1024 ----------------
// MODE 0: write bf16 to (B,H,S,DK)    (Q/K layout)
// MODE 2: write bf16 to (B,H,DK,S)    (V^T layout)
// MODE 3: write fp32 row-major (M,N)  (final output)
template<int MODE>
__global__ __launch_bounds__(256) void gemm_bt(const unsigned short* __restrict__ A,
                                               const unsigned short* __restrict__ W,
                                               void* __restrict__ Out) {
  const int K = 1024, N = 1024;
  int bx = blockIdx.x;
  int bm = bx >> 3, bn = bx & 7;          // 64 x 8 blocks of 128x128
  __shared__ __align__(16) char lA[128*128];   // 128 rows x 64 bf16 (128B), swizzled
  __shared__ __align__(16) char lB[128*128];
  int t = threadIdx.x;
  int wave = t >> 6, lane = t & 63;
  int ln15 = lane & 15, lgrp = lane >> 4;
  int wr = wave >> 1, wc = wave & 1;

  f32x4 acc[4][4];
#pragma unroll
  for (int m = 0; m < 4; ++m)
#pragma unroll
    for (int n = 0; n < 4; ++n) { f32x4 z = {0.f,0.f,0.f,0.f}; acc[m][n] = z; }

  const char* Ab = (const char*)A + (size_t)bm * 128 * (K*2);
  const char* Bb = (const char*)W + (size_t)bn * 128 * (K*2);

  for (int k0 = 0; k0 < K; k0 += 64) {
#pragma unroll
    for (int i = 0; i < 4; ++i) {
      int ch = i*256 + t;
      int a = ch << 4;                 // lds linear byte
      int r = a >> 7;                  // row (0..127)
      int cb = (a & 127) ^ ((r & 7) << 4);   // logical col bytes (pre-swizzled source)
      GLDS16(Ab + (size_t)r*(K*2) + k0*2 + cb, lA + a);
      GLDS16(Bb + (size_t)r*(K*2) + k0*2 + cb, lB + a);
    }
    __syncthreads();
#pragma unroll
    for (int kf = 0; kf < 2; ++kf) {
      int cb = kf*64 + lgrp*16;
      short8 af[4], bf[4];
#pragma unroll
      for (int m = 0; m < 4; ++m) {
        int r = wr*64 + m*16 + ln15;
        af[m] = *(const short8*)(lA + r*128 + (cb ^ ((r & 7) << 4)));
      }
#pragma unroll
      for (int n = 0; n < 4; ++n) {
        int r = wc*64 + n*16 + ln15;
        bf[n] = *(const short8*)(lB + r*128 + (cb ^ ((r & 7) << 4)));
      }
#pragma unroll
      for (int m = 0; m < 4; ++m)
#pragma unroll
        for (int n = 0; n < 4; ++n)
          acc[m][n] = __builtin_amdgcn_mfma_f32_16x16x32_bf16(af[m], bf[n], acc[m][n], 0, 0, 0);
    }
    __syncthreads();
  }

#pragma unroll
  for (int m = 0; m < 4; ++m)
#pragma unroll
    for (int n = 0; n < 4; ++n)
#pragma unroll
      for (int r = 0; r < 4; ++r) {
        int row = bm*128 + wr*64 + m*16 + lgrp*4 + r;
        int col = bn*128 + wc*64 + n*16 + ln15;
        float v = acc[m][n][r];
        if (MODE == 0) {
          int b = row >> 11, s = row & (S_-1);
          int h = col >> 6, dk = col & 63;
          ((unsigned short*)Out)[(((size_t)(b*H_ + h)*S_ + s) << 6) + dk] = f2bf(v);
        } else if (MODE == 2) {
          int b = row >> 11, s = row & (S_-1);
          int h = col >> 6, dk = col & 63;
          ((unsigned short*)Out)[(((size_t)(b*H_ + h)*DK_ + dk) * S_) + s] = f2bf(v);
        } else {
          ((float*)Out)[(size_t)row * N + col] = v;
        }
      }
}

// ---------------- RoPE (in-place, interleaved pairs), optional scale ----------------
__global__ void rope_kernel(unsigned short* __restrict__ X, const int* __restrict__ pos, float scale) {
  int idx = blockIdx.x * 256 + threadIdx.x;       // [0, 64*2048*32)
  int i = idx & 31;                               // pair index
  int s = (idx >> 5) & (S_-1);
  int bh = idx >> 16;
  unsigned short* p = X + (((size_t)bh * S_ + s) << 6) + (i << 1);
  float x1 = bf2f(p[0]), x2 = bf2f(p[1]);
  float freq = exp2f(-(float)i * (13.287712379549449f / 32.0f));  // 10000^(-i/32)
  float ang = (float)pos[s] * freq;
  float sn, cs;
  sincosf(ang, &sn, &cs);
  float o1 = (x1*cs - x2*sn) * scale;
  float o2 = (x1*sn + x2*cs) * scale;
  p[0] = f2bf(o1); p[1] = f2bf(o2);
}

// ---------------- Flash attention (causal). Q pre-scaled by 1/8. ----------------
// Q,K: (B,H,S,DK) bf16 ; VT: (B,H,DK,S) bf16 ; O: (B,S,D) bf16
__global__ __launch_bounds__(256) void attn_kernel(const unsigned short* __restrict__ Q,
                                                   const unsigned short* __restrict__ Kg,
                                                   const unsigned short* __restrict__ VT,
                                                   unsigned short* __restrict__ O) {
  int qt = blockIdx.x;          // 0..31 (64-row Q tiles)
  int bh = blockIdx.y;          // 0..63
  int b = bh >> 4, h = bh & 15;
  const unsigned short* Qp = Q + (((size_t)bh * S_ + qt*64) << 6);
  const char* Kp = (const char*)(Kg + ((size_t)bh * S_ << 6));
  const char* Vp = (const char*)(VT + (size_t)bh * DK_ * S_);

  __shared__ __align__(16) char lK[64*128];     // 64 kv x 64 dk bf16, swizzled
  __shared__ __align__(16) char lV[64*128];     // 64 dk x 64 kv bf16, swizzled
  __shared__ __align__(16) char lP[4][16*128];  // per-wave 16 q x 64 kv bf16, swizzled

  int t = threadIdx.x, wave = t >> 6, lane = t & 63;
  int ln15 = lane & 15, lgrp = lane >> 4;

  short8 qf[2];
#pragma unroll
  for (int kf = 0; kf < 2; ++kf)
    qf[kf] = *(const short8*)(Qp + (wave*16 + ln15)*64 + kf*32 + lgrp*8);

  f32x4 o[4];
#pragma unroll
  for (int d = 0; d < 4; ++d) { f32x4 z = {0.f,0.f,0.f,0.f}; o[d] = z; }
  float mi[4], li[4];
#pragma unroll
  for (int r = 0; r < 4; ++r) { mi[r] = -__builtin_inff(); li[r] = 0.f; }

  for (int kt = 0; kt <= qt; ++kt) {
    // stage K block (64x64) and V^T block (64x64)
#pragma unroll
    for (int i = 0; i < 2; ++i) {
      int ch = i*256 + t;
      int a = ch << 4;
      int r = a >> 7;
      int cb = (a & 127) ^ ((r & 7) << 4);
      GLDS16(Kp + (size_t)(kt*64 + r)*128 + cb, lK + a);
      GLDS16(Vp + (size_t)r*(S_*2) + (size_t)kt*128 + cb, lV + a);
    }
    __syncthreads();

    // QK^T : scores sc[sub][reg], q=(lgrp*4+reg), kv=sub*16+ln15
    f32x4 sc[4];
#pragma unroll
    for (int sub = 0; sub < 4; ++sub) {
      f32x4 s4 = {0.f,0.f,0.f,0.f};
#pragma unroll
      for (int kf = 0; kf < 2; ++kf) {
        int rK = sub*16 + ln15;
        int cb = kf*64 + lgrp*16;
        short8 kfr = *(const short8*)(lK + rK*128 + (cb ^ ((rK & 7) << 4)));
        s4 = __builtin_amdgcn_mfma_f32_16x16x32_bf16(qf[kf], kfr, s4, 0, 0, 0);
      }
      sc[sub] = s4;
    }
    if (kt == qt) {
#pragma unroll
      for (int sub = 0; sub < 4; ++sub)
#pragma unroll
        for (int r = 0; r < 4; ++r)
          if (sub*16 + ln15 > wave*16 + lgrp*4 + r) sc[sub][r] = -__builtin_inff();
    }

    // online softmax (rows live across the 16-lane group)
    float p[4][4];
#pragma unroll
    for (int r = 0; r < 4; ++r) {
      float mx = fmaxf(fmaxf(sc[0][r], sc[1][r]), fmaxf(sc[2][r], sc[3][r]));
#pragma unroll
      for (int d = 1; d < 16; d <<= 1) mx = fmaxf(mx, __shfl_xor(mx, d));
      float mn = fmaxf(mi[r], mx);
      float corr = exp2f((mi[r] - mn) * 1.4426950408889634f);
      mi[r] = mn;
      li[r] *= corr;
#pragma unroll
      for (int d = 0; d < 4; ++d) o[d][r] *= corr;
      float rs = 0.f;
#pragma unroll
      for (int sub = 0; sub < 4; ++sub) {
        float pv = exp2f((sc[sub][r] - mn) * 1.4426950408889634f);
        p[sub][r] = pv; rs += pv;
      }
#pragma unroll
      for (int d = 1; d < 16; d <<= 1) rs += __shfl_xor(rs, d);
      li[r] += rs;
    }

    // P -> LDS (bf16, swizzled), then PV
    char* pw = lP[wave];
#pragma unroll
    for (int r = 0; r < 4; ++r) {
      int q = lgrp*4 + r;
#pragma unroll
      for (int sub = 0; sub < 4; ++sub) {
        int cb = (sub*16 + ln15) << 1;
        *(unsigned short*)(pw + q*128 + (cb ^ ((q & 7) << 4))) = f2bf(p[sub][r]);
      }
    }
#pragma unroll
    for (int half = 0; half < 2; ++half) {
      int cb = half*64 + lgrp*16;
      int rP = ln15;
      short8 pf = *(const short8*)(pw + rP*128 + (cb ^ ((rP & 7) << 4)));
#pragma unroll
      for (int dsub = 0; dsub < 4; ++dsub) {
        int rV = dsub*16 + ln15;
        short8 vf = *(const short8*)(lV + rV*128 + (cb ^ ((rV & 7) << 4)));
        o[dsub] = __builtin_amdgcn_mfma_f32_16x16x32_bf16(pf, vf, o[dsub], 0, 0, 0);
      }
    }
    __syncthreads();
  }

  // normalize + store to (B,S,D) bf16
#pragma unroll
  for (int dsub = 0; dsub < 4; ++dsub)
#pragma unroll
    for (int r = 0; r < 4; ++r) {
      int qg = qt*64 + wave*16 + lgrp*4 + r;
      int dk = dsub*16 + ln15;
      float v = o[dsub][r] / li[r];
      O[((size_t)(b*S_ + qg) << 10) + h*64 + dk] = f2bf(v);
    }
}

extern "C" void kernel_launch(void* const* d_in, const int* in_sizes, int n_in,
                              void* d_out, int out_size, void* d_ws, size_t ws_size,
                              hipStream_t stream) {
  const float* x  = (const float*)d_in[0];
  const float* Wq = (const float*)d_in[1];
  const float* Wk = (const float*)d_in[2];
  const float* Wv = (const float*)d_in[3];
  const float* Wo = (const float*)d_in[4];
  const int* pos  = (const int*)d_in[5];

  char* ws = (char*)d_ws;
  unsigned short* xb  = (unsigned short*)(ws + 0);          // 16 MB, also reused as O
  unsigned short* wqb = (unsigned short*)(ws + 16777216);
  unsigned short* wkb = (unsigned short*)(ws + 18874368);
  unsigned short* wvb = (unsigned short*)(ws + 20971520);
  unsigned short* wob = (unsigned short*)(ws + 23068672);
  unsigned short* Qb  = (unsigned short*)(ws + 25165824);   // 16 MB
  unsigned short* Kb  = (unsigned short*)(ws + 41943040);   // 16 MB
  unsigned short* VTb = (unsigned short*)(ws + 58720256);   // 16 MB
  unsigned short* Ob  = xb;  // alias: xb dead after V projection (stream-ordered)

  cvt_kernel<<<8192, 256, 0, stream>>>(x,  xb,  2097152);
  cvt_kernel<<<1024, 256, 0, stream>>>(Wq, wqb, 262144);
  cvt_kernel<<<1024, 256, 0, stream>>>(Wk, wkb, 262144);
  cvt_kernel<<<1024, 256, 0, stream>>>(Wv, wvb, 262144);
  cvt_kernel<<<1024, 256, 0, stream>>>(Wo, wob, 262144);

  gemm_bt<0><<<512, 256, 0, stream>>>(xb, wqb, Qb);
  gemm_bt<0><<<512, 256, 0, stream>>>(xb, wkb, Kb);
  gemm_bt<2><<<512, 256, 0, stream>>>(xb, wvb, VTb);

  rope_kernel<<<16384, 256, 0, stream>>>(Qb, pos, 0.125f);  // fold 1/sqrt(DK) into Q
  rope_kernel<<<16384, 256, 0, stream>>>(Kb, pos, 1.0f);

  attn_kernel<<<dim3(32, 64), 256, 0, stream>>>(Qb, Kb, VTb, Ob);

  gemm_bt<3><<<512, 256, 0, stream>>>(Ob, wob, d_out);
}

// Round 2
// 289.458 us; speedup vs baseline: 1.4352x; 1.4352x over previous
//
#include <hip/hip_runtime.h>
#include <stdint.h>

#define B_ 4
#define S_ 2048
#define D_ 1024
#define H_ 16
#define DK_ 64
#define M_ (B_*S_)   // 8192

typedef __attribute__((ext_vector_type(8))) short short8;
typedef __attribute__((ext_vector_type(4))) float f32x4;

static __device__ __forceinline__ float bf2f(unsigned short s) {
  union { unsigned u; float f; } v; v.u = ((unsigned)s) << 16; return v.f;
}
static __device__ __forceinline__ unsigned short f2bf(float f) {
  union { float f; unsigned u; } v; v.f = f;
  unsigned r = v.u + 0x7fffu + ((v.u >> 16) & 1u);
  return (unsigned short)(r >> 16);
}

#define GLDS16(g, l) __builtin_amdgcn_global_load_lds( \
    (const __attribute__((address_space(1))) unsigned int*)(g), \
    (__attribute__((address_space(3))) unsigned int*)(l), 16, 0, 0)

// ---------------- fp32 -> bf16 convert ----------------
__global__ void cvt_kernel(const float* __restrict__ in, unsigned short* __restrict__ out, int n4) {
  int i = blockIdx.x * 256 + threadIdx.x;
  if (i >= n4) return;
  float4 v = ((const float4*)in)[i];
  ushort4 o;
  o.x = f2bf(v.x); o.y = f2bf(v.y); o.z = f2bf(v.z); o.w = f2bf(v.w);
  ((ushort4*)out)[i] = o;
}

// ---------------- GEMM: C[M,N] = A[M,K] * W[N,K]^T, M=8192,N=K=1024 ----------------
// MODE 0: write bf16 to (B,H,S,DK)    (Q/K layout)
// MODE 2: write bf16 to (B,H,DK,S)    (V^T layout)
// MODE 3: write fp32 row-major (M,N)  (final output)
template<int MODE>
__global__ __launch_bounds__(256) void gemm_bt(const unsigned short* __restrict__ A,
                                               const unsigned short* __restrict__ W,
                                               void* __restrict__ Out) {
  const int K = 1024, N = 1024;
  int bx = blockIdx.x;
  int bm = bx >> 3, bn = bx & 7;          // 64 x 8 blocks of 128x128
  __shared__ __align__(16) char lA[128*128];   // 128 rows x 64 bf16 (128B), swizzled
  __shared__ __align__(16) char lB[128*128];
  int t = threadIdx.x;
  int wave = t >> 6, lane = t & 63;
  int ln15 = lane & 15, lgrp = lane >> 4;
  int wr = wave >> 1, wc = wave & 1;

  f32x4 acc[4][4];
#pragma unroll
  for (int m = 0; m < 4; ++m)
#pragma unroll
    for (int n = 0; n < 4; ++n) { f32x4 z = {0.f,0.f,0.f,0.f}; acc[m][n] = z; }

  const char* Ab = (const char*)A + (size_t)bm * 128 * (K*2);
  const char* Bb = (const char*)W + (size_t)bn * 128 * (K*2);

  for (int k0 = 0; k0 < K; k0 += 64) {
#pragma unroll
    for (int i = 0; i < 4; ++i) {
      int ch = i*256 + t;
      int a = ch << 4;                 // lds linear byte
      int r = a >> 7;                  // row (0..127)
      int cb = (a & 127) ^ ((r & 7) << 4);   // logical col bytes (pre-swizzled source)
      GLDS16(Ab + (size_t)r*(K*2) + k0*2 + cb, lA + a);
      GLDS16(Bb + (size_t)r*(K*2) + k0*2 + cb, lB + a);
    }
    __syncthreads();
#pragma unroll
    for (int kf = 0; kf < 2; ++kf) {
      int cb = kf*64 + lgrp*16;
      short8 af[4], bf[4];
#pragma unroll
      for (int m = 0; m < 4; ++m) {
        int r = wr*64 + m*16 + ln15;
        af[m] = *(const short8*)(lA + r*128 + (cb ^ ((r & 7) << 4)));
      }
#pragma unroll
      for (int n = 0; n < 4; ++n) {
        int r = wc*64 + n*16 + ln15;
        bf[n] = *(const short8*)(lB + r*128 + (cb ^ ((r & 7) << 4)));
      }
#pragma unroll
      for (int m = 0; m < 4; ++m)
#pragma unroll
        for (int n = 0; n < 4; ++n)
          acc[m][n] = __builtin_amdgcn_mfma_f32_16x16x32_bf16(af[m], bf[n], acc[m][n], 0, 0, 0);
    }
    __syncthreads();
  }

#pragma unroll
  for (int m = 0; m < 4; ++m)
#pragma unroll
    for (int n = 0; n < 4; ++n)
#pragma unroll
      for (int r = 0; r < 4; ++r) {
        int row = bm*128 + wr*64 + m*16 + lgrp*4 + r;
        int col = bn*128 + wc*64 + n*16 + ln15;
        float v = acc[m][n][r];
        if (MODE == 0) {
          int b = row >> 11, s = row & (S_-1);
          int h = col >> 6, dk = col & 63;
          ((unsigned short*)Out)[(((size_t)(b*H_ + h)*S_ + s) << 6) + dk] = f2bf(v);
        } else if (MODE == 2) {
          int b = row >> 11, s = row & (S_-1);
          int h = col >> 6, dk = col & 63;
          ((unsigned short*)Out)[(((size_t)(b*H_ + h)*DK_ + dk) * S_) + s] = f2bf(v);
        } else {
          ((float*)Out)[(size_t)row * N + col] = v;
        }
      }
}

// ---------------- RoPE (in-place, interleaved pairs), optional scale ----------------
__global__ void rope_kernel(unsigned short* __restrict__ X, const int* __restrict__ pos, float scale) {
  int idx = blockIdx.x * 256 + threadIdx.x;       // [0, 64*2048*32)
  int i = idx & 31;                               // pair index
  int s = (idx >> 5) & (S_-1);
  int bh = idx >> 16;
  unsigned short* p = X + (((size_t)bh * S_ + s) << 6) + (i << 1);
  float x1 = bf2f(p[0]), x2 = bf2f(p[1]);
  float freq = exp2f(-(float)i * (13.287712379549449f / 32.0f));  // 10000^(-i/32)
  float ang = (float)pos[s] * freq;
  float sn, cs;
  sincosf(ang, &sn, &cs);
  float o1 = (x1*cs - x2*sn) * scale;
  float o2 = (x1*sn + x2*cs) * scale;
  p[0] = f2bf(o1); p[1] = f2bf(o2);
}

// ---------------- Flash attention (causal). Q pre-scaled by 1/8. ----------------
// Q,K: (B,H,S,DK) bf16 ; VT: (B,H,DK,S) bf16 ; O: (B,S,D) bf16
// Block = 128 Q rows (4 waves x 32 rows, 2 groups of 16), KV tiles of 64,
// double-buffered K/V staging, heavy-diagonal blocks launched first.
__global__ __launch_bounds__(256) void attn_kernel(const unsigned short* __restrict__ Q,
                                                   const unsigned short* __restrict__ Kg,
                                                   const unsigned short* __restrict__ VT,
                                                   unsigned short* __restrict__ O) {
  int bid = blockIdx.x;
  int bh = bid & 63;                 // head id (b*16+h)
  int qt = 15 - (bid >> 6);          // heavy (large-qt) blocks dispatched first
  int b = bh >> 4, h = bh & 15;
  const unsigned short* Qp = Q + (((size_t)bh * S_ + qt*128) << 6);
  const char* Kp = (const char*)(Kg + ((size_t)bh * S_ << 6));
  const char* Vp = (const char*)(VT + (size_t)bh * DK_ * S_);

  __shared__ __align__(16) char lK[2][64*128];   // dbuf: 64 kv x 64 dk bf16, swizzled
  __shared__ __align__(16) char lV[2][64*128];   // dbuf: 64 dk x 64 kv bf16, swizzled
  __shared__ __align__(16) char lP[4][16*128];   // per-wave 16 q x 64 kv bf16, swizzled

  int t = threadIdx.x, wave = t >> 6, lane = t & 63;
  int ln15 = lane & 15, lgrp = lane >> 4;

  // Q fragments: 2 row-groups of 16, k = kf*32 + lgrp*8
  short8 qf[2][2];
#pragma unroll
  for (int g = 0; g < 2; ++g)
#pragma unroll
    for (int kf = 0; kf < 2; ++kf)
      qf[g][kf] = *(const short8*)(Qp + (wave*32 + g*16 + ln15)*64 + kf*32 + lgrp*8);

  f32x4 o[2][4];
#pragma unroll
  for (int g = 0; g < 2; ++g)
#pragma unroll
    for (int d = 0; d < 4; ++d) { f32x4 z = {0.f,0.f,0.f,0.f}; o[g][d] = z; }
  float mi[2][4], li[2][4];
#pragma unroll
  for (int g = 0; g < 2; ++g)
#pragma unroll
    for (int r = 0; r < 4; ++r) { mi[g][r] = -__builtin_inff(); li[g][r] = 0.f; }

  const int ktmax = 2*qt + 1;

  // ---- staging helper (inlined twice): stages K tile and V^T tile for kt into buf ----
#define STAGE_KV(bufi, ktv) do { \
    _Pragma("unroll") \
    for (int i_ = 0; i_ < 2; ++i_) { \
      int ch_ = i_*256 + t; \
      int a_ = ch_ << 4; \
      int r_ = a_ >> 7; \
      int cb_ = (a_ & 127) ^ ((r_ & 7) << 4); \
      GLDS16(Kp + (size_t)((ktv)*64 + r_)*128 + cb_, lK[bufi] + a_); \
      GLDS16(Vp + (size_t)r_*(S_*2) + (size_t)(ktv)*128 + cb_, lV[bufi] + a_); \
    } \
  } while (0)

  STAGE_KV(0, 0);
  __syncthreads();   // compiler drains vmcnt(0) before barrier -> buf0 ready

  int cur = 0;
  for (int kt = 0; kt <= ktmax; ++kt) {
    // prefetch next KV tile into the other buffer (latency hides under compute)
    if (kt < ktmax) STAGE_KV(cur ^ 1, kt + 1);

    const char* cK = lK[cur];
    const char* cV = lV[cur];
    bool diag = (kt >= 2*qt);

#pragma unroll
    for (int g = 0; g < 2; ++g) {
      // ---- QK^T : sc[sub][reg], q = g-group row lgrp*4+reg, kv = sub*16+ln15 ----
      f32x4 sc[4];
      __builtin_amdgcn_s_setprio(1);
#pragma unroll
      for (int sub = 0; sub < 4; ++sub) {
        f32x4 s4 = {0.f,0.f,0.f,0.f};
        int rK = sub*16 + ln15;
#pragma unroll
        for (int kf = 0; kf < 2; ++kf) {
          int cb = kf*64 + lgrp*16;
          short8 kfr = *(const short8*)(cK + rK*128 + (cb ^ ((rK & 7) << 4)));
          s4 = __builtin_amdgcn_mfma_f32_16x16x32_bf16(qf[g][kf], kfr, s4, 0, 0, 0);
        }
        sc[sub] = s4;
      }
      __builtin_amdgcn_s_setprio(0);

      if (diag) {
        int qg = qt*128 + wave*32 + g*16 + lgrp*4;
#pragma unroll
        for (int sub = 0; sub < 4; ++sub) {
          int kv = kt*64 + sub*16 + ln15;
#pragma unroll
          for (int r = 0; r < 4; ++r)
            if (kv > qg + r) sc[sub][r] = -__builtin_inff();
        }
      }

      // ---- online softmax (rows live across the 16-lane group) ----
      float p[4][4];
#pragma unroll
      for (int r = 0; r < 4; ++r) {
        float mx = fmaxf(fmaxf(sc[0][r], sc[1][r]), fmaxf(sc[2][r], sc[3][r]));
#pragma unroll
        for (int d = 1; d < 16; d <<= 1) mx = fmaxf(mx, __shfl_xor(mx, d));
        float mn = fmaxf(mi[g][r], mx);
        float corr = exp2f((mi[g][r] - mn) * 1.4426950408889634f);
        mi[g][r] = mn;
        li[g][r] *= corr;
#pragma unroll
        for (int d = 0; d < 4; ++d) o[g][d][r] *= corr;
        float rs = 0.f;
#pragma unroll
        for (int sub = 0; sub < 4; ++sub) {
          float pv = exp2f((sc[sub][r] - mn) * 1.4426950408889634f);
          p[sub][r] = pv; rs += pv;
        }
#pragma unroll
        for (int d = 1; d < 16; d <<= 1) rs += __shfl_xor(rs, d);
        li[g][r] += rs;
      }

      // ---- P -> per-wave LDS (swizzled), then PV ----
      char* pw = lP[wave];
#pragma unroll
      for (int r = 0; r < 4; ++r) {
        int q = lgrp*4 + r;
#pragma unroll
        for (int sub = 0; sub < 4; ++sub) {
          int cb = (sub*16 + ln15) << 1;
          *(unsigned short*)(pw + q*128 + (cb ^ ((q & 7) << 4))) = f2bf(p[sub][r]);
        }
      }
      __builtin_amdgcn_s_setprio(1);
#pragma unroll
      for (int half = 0; half < 2; ++half) {
        int cb = half*64 + lgrp*16;
        int rP = ln15;
        short8 pf = *(const short8*)(pw + rP*128 + (cb ^ ((rP & 7) << 4)));
#pragma unroll
        for (int dsub = 0; dsub < 4; ++dsub) {
          int rV = dsub*16 + ln15;
          short8 vf = *(const short8*)(cV + rV*128 + (cb ^ ((rV & 7) << 4)));
          o[g][dsub] = __builtin_amdgcn_mfma_f32_16x16x32_bf16(pf, vf, o[g][dsub], 0, 0, 0);
        }
      }
      __builtin_amdgcn_s_setprio(0);
    }

    __syncthreads();   // drains this wave's prefetch vmcnt + joins; buffers swap safely
    cur ^= 1;
  }
#undef STAGE_KV

  // normalize + store to (B,S,D) bf16
#pragma unroll
  for (int g = 0; g < 2; ++g)
#pragma unroll
    for (int dsub = 0; dsub < 4; ++dsub)
#pragma unroll
      for (int r = 0; r < 4; ++r) {
        int qg = qt*128 + wave*32 + g*16 + lgrp*4 + r;
        int dk = dsub*16 + ln15;
        float v = o[g][dsub][r] / li[g][r];
        O[((size_t)(b*S_ + qg) << 10) + h*64 + dk] = f2bf(v);
      }
}

extern "C" void kernel_launch(void* const* d_in, const int* in_sizes, int n_in,
                              void* d_out, int out_size, void* d_ws, size_t ws_size,
                              hipStream_t stream) {
  const float* x  = (const float*)d_in[0];
  const float* Wq = (const float*)d_in[1];
  const float* Wk = (const float*)d_in[2];
  const float* Wv = (const float*)d_in[3];
  const float* Wo = (const float*)d_in[4];
  const int* pos  = (const int*)d_in[5];

  char* ws = (char*)d_ws;
  unsigned short* xb  = (unsigned short*)(ws + 0);          // 16 MB, also reused as O
  unsigned short* wqb = (unsigned short*)(ws + 16777216);
  unsigned short* wkb = (unsigned short*)(ws + 18874368);
  unsigned short* wvb = (unsigned short*)(ws + 20971520);
  unsigned short* wob = (unsigned short*)(ws + 23068672);
  unsigned short* Qb  = (unsigned short*)(ws + 25165824);   // 16 MB
  unsigned short* Kb  = (unsigned short*)(ws + 41943040);   // 16 MB
  unsigned short* VTb = (unsigned short*)(ws + 58720256);   // 16 MB
  unsigned short* Ob  = xb;  // alias: xb dead after V projection (stream-ordered)

  cvt_kernel<<<8192, 256, 0, stream>>>(x,  xb,  2097152);
  cvt_kernel<<<1024, 256, 0, stream>>>(Wq, wqb, 262144);
  cvt_kernel<<<1024, 256, 0, stream>>>(Wk, wkb, 262144);
  cvt_kernel<<<1024, 256, 0, stream>>>(Wv, wvb, 262144);
  cvt_kernel<<<1024, 256, 0, stream>>>(Wo, wob, 262144);

  gemm_bt<0><<<512, 256, 0, stream>>>(xb, wqb, Qb);
  gemm_bt<0><<<512, 256, 0, stream>>>(xb, wkb, Kb);
  gemm_bt<2><<<512, 256, 0, stream>>>(xb, wvb, VTb);

  rope_kernel<<<16384, 256, 0, stream>>>(Qb, pos, 0.125f);  // fold 1/sqrt(DK) into Q
  rope_kernel<<<16384, 256, 0, stream>>>(Kb, pos, 1.0f);

  attn_kernel<<<1024, 256, 0, stream>>>(Qb, Kb, VTb, Ob);

  gemm_bt<3><<<512, 256, 0, stream>>>(Ob, wob, d_out);
}

// Round 3
// 223.325 us; speedup vs baseline: 1.8603x; 1.2961x over previous
//
#include <hip/hip_runtime.h>
#include <stdint.h>

#define B_ 4
#define S_ 2048
#define D_ 1024
#define H_ 16
#define DK_ 64
#define M_ (B_*S_)   // 8192

typedef __attribute__((ext_vector_type(8))) short short8;
typedef __attribute__((ext_vector_type(4))) float f32x4;
typedef __attribute__((ext_vector_type(16))) float f32x16;
typedef __attribute__((ext_vector_type(2))) unsigned int u32x2;

static __device__ __forceinline__ float bf2f(unsigned short s) {
  union { unsigned u; float f; } v; v.u = ((unsigned)s) << 16; return v.f;
}
static __device__ __forceinline__ unsigned short f2bf(float f) {
  union { float f; unsigned u; } v; v.f = f;
  unsigned r = v.u + 0x7fffu + ((v.u >> 16) & 1u);
  return (unsigned short)(r >> 16);
}
static __device__ __forceinline__ unsigned cvtpk_bf16(float lo, float hi) {
  unsigned r;
  asm("v_cvt_pk_bf16_f32 %0, %1, %2" : "=v"(r) : "v"(lo), "v"(hi));
  return r;
}

#define GLDS16(g, l) __builtin_amdgcn_global_load_lds( \
    (const __attribute__((address_space(1))) unsigned int*)(g), \
    (__attribute__((address_space(3))) unsigned int*)(l), 16, 0, 0)

// ---------------- fp32 -> bf16 convert ----------------
__global__ void cvt_kernel(const float* __restrict__ in, unsigned short* __restrict__ out, int n4) {
  int i = blockIdx.x * 256 + threadIdx.x;
  if (i >= n4) return;
  float4 v = ((const float4*)in)[i];
  ushort4 o;
  o.x = f2bf(v.x); o.y = f2bf(v.y); o.z = f2bf(v.z); o.w = f2bf(v.w);
  ((ushort4*)out)[i] = o;
}

// ---------------- GEMM: C[M,N] = A[M,K] * W[N,K]^T, M=8192,N=K=1024 ----------------
// MODE 0: write bf16 to (B,H,S,DK)    (Q/K layout)
// MODE 2: write bf16 to (B,H,DK,S)    (V^T layout)
// MODE 3: write fp32 row-major (M,N)  (final output)
template<int MODE>
__global__ __launch_bounds__(256) void gemm_bt(const unsigned short* __restrict__ A,
                                               const unsigned short* __restrict__ W,
                                               void* __restrict__ Out) {
  const int K = 1024, N = 1024;
  int bx = blockIdx.x;
  int bm = bx >> 3, bn = bx & 7;          // 64 x 8 blocks of 128x128
  __shared__ __align__(16) char lA[128*128];   // 128 rows x 64 bf16 (128B), swizzled
  __shared__ __align__(16) char lB[128*128];
  int t = threadIdx.x;
  int wave = t >> 6, lane = t & 63;
  int ln15 = lane & 15, lgrp = lane >> 4;
  int wr = wave >> 1, wc = wave & 1;

  f32x4 acc[4][4];
#pragma unroll
  for (int m = 0; m < 4; ++m)
#pragma unroll
    for (int n = 0; n < 4; ++n) { f32x4 z = {0.f,0.f,0.f,0.f}; acc[m][n] = z; }

  const char* Ab = (const char*)A + (size_t)bm * 128 * (K*2);
  const char* Bb = (const char*)W + (size_t)bn * 128 * (K*2);

  for (int k0 = 0; k0 < K; k0 += 64) {
#pragma unroll
    for (int i = 0; i < 4; ++i) {
      int ch = i*256 + t;
      int a = ch << 4;                 // lds linear byte
      int r = a >> 7;                  // row (0..127)
      int cb = (a & 127) ^ ((r & 7) << 4);   // logical col bytes (pre-swizzled source)
      GLDS16(Ab + (size_t)r*(K*2) + k0*2 + cb, lA + a);
      GLDS16(Bb + (size_t)r*(K*2) + k0*2 + cb, lB + a);
    }
    __syncthreads();
#pragma unroll
    for (int kf = 0; kf < 2; ++kf) {
      int cb = kf*64 + lgrp*16;
      short8 af[4], bf[4];
#pragma unroll
      for (int m = 0; m < 4; ++m) {
        int r = wr*64 + m*16 + ln15;
        af[m] = *(const short8*)(lA + r*128 + (cb ^ ((r & 7) << 4)));
      }
#pragma unroll
      for (int n = 0; n < 4; ++n) {
        int r = wc*64 + n*16 + ln15;
        bf[n] = *(const short8*)(lB + r*128 + (cb ^ ((r & 7) << 4)));
      }
#pragma unroll
      for (int m = 0; m < 4; ++m)
#pragma unroll
        for (int n = 0; n < 4; ++n)
          acc[m][n] = __builtin_amdgcn_mfma_f32_16x16x32_bf16(af[m], bf[n], acc[m][n], 0, 0, 0);
    }
    __syncthreads();
  }

#pragma unroll
  for (int m = 0; m < 4; ++m)
#pragma unroll
    for (int n = 0; n < 4; ++n)
#pragma unroll
      for (int r = 0; r < 4; ++r) {
        int row = bm*128 + wr*64 + m*16 + lgrp*4 + r;
        int col = bn*128 + wc*64 + n*16 + ln15;
        float v = acc[m][n][r];
        if (MODE == 0) {
          int b = row >> 11, s = row & (S_-1);
          int h = col >> 6, dk = col & 63;
          ((unsigned short*)Out)[(((size_t)(b*H_ + h)*S_ + s) << 6) + dk] = f2bf(v);
        } else if (MODE == 2) {
          int b = row >> 11, s = row & (S_-1);
          int h = col >> 6, dk = col & 63;
          ((unsigned short*)Out)[(((size_t)(b*H_ + h)*DK_ + dk) * S_) + s] = f2bf(v);
        } else {
          ((float*)Out)[(size_t)row * N + col] = v;
        }
      }
}

// ---------------- RoPE (in-place, interleaved pairs), optional scale ----------------
__global__ void rope_kernel(unsigned short* __restrict__ X, const int* __restrict__ pos, float scale) {
  int idx = blockIdx.x * 256 + threadIdx.x;       // [0, 64*2048*32)
  int i = idx & 31;                               // pair index
  int s = (idx >> 5) & (S_-1);
  int bh = idx >> 16;
  unsigned short* p = X + (((size_t)bh * S_ + s) << 6) + (i << 1);
  float x1 = bf2f(p[0]), x2 = bf2f(p[1]);
  float freq = exp2f(-(float)i * (13.287712379549449f / 32.0f));  // 10000^(-i/32)
  float ang = (float)pos[s] * freq;
  float sn, cs;
  sincosf(ang, &sn, &cs);
  float o1 = (x1*cs - x2*sn) * scale;
  float o2 = (x1*sn + x2*cs) * scale;
  p[0] = f2bf(o1); p[1] = f2bf(o2);
}

// ---------------- Flash attention, swapped-operand 32x32 structure ----------------
// Q,K: (B,H,S,DK) bf16 (Q pre-scaled 1/8) ; VT: (B,H,DK,S) bf16 ; O: (B,S,D) bf16
// Block = 128 Q rows (4 waves x 32), KV tiles 64, dbuf staging.
// QK^T computed as mfma(K,Q) -> S[kv][q] (q = lane&31, kv in regs): softmax in-register.
// PV computed as mfma(V^T,P) -> O[dk][q]: rescale factor lane-uniform.
__global__ __launch_bounds__(256) void attn_kernel(const unsigned short* __restrict__ Q,
                                                   const unsigned short* __restrict__ Kg,
                                                   const unsigned short* __restrict__ VT,
                                                   unsigned short* __restrict__ O) {
  const float L2E = 1.4426950408889634f;
  int bid = blockIdx.x;
  int bh = bid & 63;
  int qt = 15 - (bid >> 6);          // heavy blocks first
  int b = bh >> 4, h = bh & 15;
  const int qbase = qt * 128;
  const unsigned short* Qp = Q + (((size_t)bh * S_ + qbase) << 6);
  const char* Kp = (const char*)(Kg + ((size_t)bh * S_ << 6));
  const char* Vp = (const char*)(VT + (size_t)bh * DK_ * S_);

  __shared__ __align__(16) char lK[2][64*128];   // [kv][dk] bf16, swizzled
  __shared__ __align__(16) char lV[2][64*128];   // [dk][kv] bf16, swizzled

  int t = threadIdx.x, wave = t >> 6, lane = t & 63;
  int ln31 = lane & 31, hi = lane >> 5;
  int qw = wave * 32;
  int qg = qbase + qw + ln31;        // this lane's q row

  // Q fragments (B-operand): row q = ln31, k = kk*16 + hi*8 + [0,8)
  short8 qf[4];
#pragma unroll
  for (int kk = 0; kk < 4; ++kk)
    qf[kk] = *(const short8*)(Qp + (size_t)(qw + ln31)*64 + kk*16 + hi*8);

  f32x16 oc[2];
#pragma unroll
  for (int dh = 0; dh < 2; ++dh)
#pragma unroll
    for (int r = 0; r < 16; ++r) oc[dh][r] = 0.f;
  float mi = -__builtin_inff(), li = 0.f;

  const int nt = 2*qt + 2;           // kv tiles

#define STAGE_KV(bufi, ktv) do { \
    _Pragma("unroll") \
    for (int i_ = 0; i_ < 2; ++i_) { \
      int ch_ = i_*256 + t; \
      int a_ = ch_ << 4; \
      int r_ = a_ >> 7; \
      int cb_ = (a_ & 127) ^ ((r_ & 7) << 4); \
      GLDS16(Kp + (size_t)((ktv)*64 + r_)*128 + cb_, lK[bufi] + a_); \
      GLDS16(Vp + (size_t)r_*(S_*2) + (size_t)(ktv)*128 + cb_, lV[bufi] + a_); \
    } \
  } while (0)

  STAGE_KV(0, 0);
  __syncthreads();

  int cur = 0;
  for (int kt = 0; kt < nt; ++kt) {
    if (kt + 1 < nt) STAGE_KV(cur ^ 1, kt + 1);

    const char* cK = lK[cur];
    const char* cV = lV[cur];
    bool active = (kt*64 <= qbase + qw + 31);          // wave-uniform
    bool diag   = (kt*64 + 63 > qbase + qw);           // wave-uniform

    if (active) {
      // ---- QK^T (swapped): sc[t2] = D[kv_local][q] ----
      f32x16 sc[2];
      __builtin_amdgcn_s_setprio(1);
#pragma unroll
      for (int t2 = 0; t2 < 2; ++t2) {
        f32x16 a;
#pragma unroll
        for (int r = 0; r < 16; ++r) a[r] = 0.f;
        int rK = t2*32 + ln31;
        int swz = (rK & 7) << 4;
#pragma unroll
        for (int kk = 0; kk < 4; ++kk) {
          short8 kfr = *(const short8*)(cK + rK*128 + ((kk*32 + hi*16) ^ swz));
          a = __builtin_amdgcn_mfma_f32_32x32x16_bf16(kfr, qf[kk], a, 0, 0, 0);
        }
        sc[t2] = a;
      }
      __builtin_amdgcn_s_setprio(0);

      if (diag) {
#pragma unroll
        for (int t2 = 0; t2 < 2; ++t2)
#pragma unroll
          for (int r = 0; r < 16; ++r) {
            int kv = kt*64 + t2*32 + (r & 3) + 8*(r >> 2) + 4*hi;
            if (kv > qg) sc[t2][r] = -__builtin_inff();
          }
      }

      // ---- in-register softmax: row lives in this lane (+ partner lane^32) ----
      float mx = sc[0][0];
#pragma unroll
      for (int r = 1; r < 16; ++r) mx = fmaxf(mx, sc[0][r]);
#pragma unroll
      for (int r = 0; r < 16; ++r) mx = fmaxf(mx, sc[1][r]);
      mx = fmaxf(mx, __shfl_xor(mx, 32));

      if (!__all(mx - mi <= 8.f)) {          // defer-max (T13)
        float mn = fmaxf(mi, mx);
        float corr = exp2f((mi - mn) * L2E);
        li *= corr;
#pragma unroll
        for (int dh = 0; dh < 2; ++dh)
#pragma unroll
          for (int r = 0; r < 16; ++r) oc[dh][r] *= corr;
        mi = mn;
      }

      float ls = 0.f;
#pragma unroll
      for (int t2 = 0; t2 < 2; ++t2)
#pragma unroll
        for (int r = 0; r < 16; ++r) {
          float pv = exp2f((sc[t2][r] - mi) * L2E);
          sc[t2][r] = pv; ls += pv;
        }
      li += ls;

      // ---- P -> bf16 frags in-register (T12) + PV (swapped) ----
#pragma unroll
      for (int kk = 0; kk < 4; ++kk) {
        int base = 8*(kk & 1), tt = kk >> 1;
        unsigned P0 = cvtpk_bf16(sc[tt][base+0], sc[tt][base+1]);
        unsigned P1 = cvtpk_bf16(sc[tt][base+2], sc[tt][base+3]);
        unsigned Q0 = cvtpk_bf16(sc[tt][base+4], sc[tt][base+5]);
        unsigned Q1 = cvtpk_bf16(sc[tt][base+6], sc[tt][base+7]);
        u32x2 r01 = __builtin_amdgcn_permlane32_swap(P0, Q0, false, false);
        u32x2 s01 = __builtin_amdgcn_permlane32_swap(P1, Q1, false, false);
        union { unsigned u[4]; short8 s8; } pf;
        pf.u[0] = r01[0]; pf.u[1] = s01[0]; pf.u[2] = r01[1]; pf.u[3] = s01[1];
        __builtin_amdgcn_s_setprio(1);
#pragma unroll
        for (int dh = 0; dh < 2; ++dh) {
          int rV = dh*32 + ln31;
          short8 vfr = *(const short8*)(cV + rV*128 + (((kk*32 + hi*16)) ^ ((rV & 7) << 4)));
          oc[dh] = __builtin_amdgcn_mfma_f32_32x32x16_bf16(vfr, pf.s8, oc[dh], 0, 0, 0);
        }
        __builtin_amdgcn_s_setprio(0);
      }
    }

    __syncthreads();
    cur ^= 1;
  }
#undef STAGE_KV

  // ---- epilogue: combine li with partner lane, normalize, store ----
  float lf = li + __shfl_xor(li, 32);
  float rinv = 1.0f / lf;
#pragma unroll
  for (int dh = 0; dh < 2; ++dh)
#pragma unroll
    for (int rg = 0; rg < 4; ++rg) {
      ushort4 pk4;
      pk4.x = f2bf(oc[dh][rg*4+0] * rinv);
      pk4.y = f2bf(oc[dh][rg*4+1] * rinv);
      pk4.z = f2bf(oc[dh][rg*4+2] * rinv);
      pk4.w = f2bf(oc[dh][rg*4+3] * rinv);
      int dk = dh*32 + 8*rg + 4*hi;
      *(ushort4*)(O + (((size_t)(b*S_ + qg)) << 10) + h*64 + dk) = pk4;
    }
}

extern "C" void kernel_launch(void* const* d_in, const int* in_sizes, int n_in,
                              void* d_out, int out_size, void* d_ws, size_t ws_size,
                              hipStream_t stream) {
  const float* x  = (const float*)d_in[0];
  const float* Wq = (const float*)d_in[1];
  const float* Wk = (const float*)d_in[2];
  const float* Wv = (const float*)d_in[3];
  const float* Wo = (const float*)d_in[4];
  const int* pos  = (const int*)d_in[5];

  char* ws = (char*)d_ws;
  unsigned short* xb  = (unsigned short*)(ws + 0);          // 16 MB, also reused as O
  unsigned short* wqb = (unsigned short*)(ws + 16777216);
  unsigned short* wkb = (unsigned short*)(ws + 18874368);
  unsigned short* wvb = (unsigned short*)(ws + 20971520);
  unsigned short* wob = (unsigned short*)(ws + 23068672);
  unsigned short* Qb  = (unsigned short*)(ws + 25165824);   // 16 MB
  unsigned short* Kb  = (unsigned short*)(ws + 41943040);   // 16 MB
  unsigned short* VTb = (unsigned short*)(ws + 58720256);   // 16 MB
  unsigned short* Ob  = xb;  // alias: xb dead after V projection (stream-ordered)

  cvt_kernel<<<8192, 256, 0, stream>>>(x,  xb,  2097152);
  cvt_kernel<<<1024, 256, 0, stream>>>(Wq, wqb, 262144);
  cvt_kernel<<<1024, 256, 0, stream>>>(Wk, wkb, 262144);
  cvt_kernel<<<1024, 256, 0, stream>>>(Wv, wvb, 262144);
  cvt_kernel<<<1024, 256, 0, stream>>>(Wo, wob, 262144);

  gemm_bt<0><<<512, 256, 0, stream>>>(xb, wqb, Qb);
  gemm_bt<0><<<512, 256, 0, stream>>>(xb, wkb, Kb);
  gemm_bt<2><<<512, 256, 0, stream>>>(xb, wvb, VTb);

  rope_kernel<<<16384, 256, 0, stream>>>(Qb, pos, 0.125f);  // fold 1/sqrt(DK) into Q
  rope_kernel<<<16384, 256, 0, stream>>>(Kb, pos, 1.0f);

  attn_kernel<<<1024, 256, 0, stream>>>(Qb, Kb, VTb, Ob);

  gemm_bt<3><<<512, 256, 0, stream>>>(Ob, wob, d_out);
}